// Round 11
// baseline (211.739 us; speedup 1.0000x reference)
//
#include <hip/hip_runtime.h>
#include <math.h>

// Problem constants
#define H_    8
#define DH    64
#define NN    512
#define KADJ  16
#define FF    512      // H_*Dh
#define BTOT  24       // B*T
#define ROWS  12288    // B*T*N
#define SN_   27
#define EPS_  1e-5f

typedef short short8 __attribute__((ext_vector_type(8)));
typedef float f32x4  __attribute__((ext_vector_type(4)));

__device__ __forceinline__ ushort f2bf(float x) {
    uint u = __float_as_uint(x);
    u += 0x7FFFu + ((u >> 16) & 1u);
    return (ushort)(u >> 16);
}
__device__ __forceinline__ float bf2f(ushort h) {
    return __uint_as_float(((uint)h) << 16);
}

// async global->LDS, 16B per lane; LDS dest = wave-uniform base + lane*16
__device__ __forceinline__ void gload_lds16(const ushort* g, ushort* l) {
    __builtin_amdgcn_global_load_lds(
        (const __attribute__((address_space(1))) unsigned int*)g,
        (__attribute__((address_space(3))) unsigned int*)l,
        16, 0, 0);
}

// ---------------------------------------------------------------------------
// Kernel 1: x_ = x + pos, emitted directly as bf16 hi/lo planes
// ---------------------------------------------------------------------------
__global__ __launch_bounds__(256) void add_pos_bf16(
    const float* __restrict__ x,
    const float* __restrict__ spa_val, const float* __restrict__ spa_vec,
    const float* __restrict__ tem_val, const float* __restrict__ tem_vec,
    ushort* __restrict__ xh, ushort* __restrict__ xl)
{
    int i = blockIdx.x * 256 + threadIdx.x;   // float4 index, 1,572,864 total
    int f4  = i & 127;
    int row = i >> 7;
    int n   = row & (NN - 1);

    float4 xv = reinterpret_cast<const float4*>(x)[i];
    float4 sv = reinterpret_cast<const float4*>(spa_vec)[n * 128 + f4];
    float4 tv = reinterpret_cast<const float4*>(tem_vec)[n * 128 + f4];
    float4 se = reinterpret_cast<const float4*>(spa_val)[f4];
    float4 te = reinterpret_cast<const float4*>(tem_val)[f4];
    float r0 = xv.x + sv.x * se.x + tv.x * te.x;
    float r1 = xv.y + sv.y * se.y + tv.y * te.y;
    float r2 = xv.z + sv.z * se.z + tv.z * te.z;
    float r3 = xv.w + sv.w * se.w + tv.w * te.w;
    ushort h0 = f2bf(r0), h1 = f2bf(r1), h2 = f2bf(r2), h3 = f2bf(r3);
    reinterpret_cast<ushort4*>(xh)[i] = make_ushort4(h0, h1, h2, h3);
    reinterpret_cast<ushort4*>(xl)[i] = make_ushort4(
        f2bf(r0 - bf2f(h0)), f2bf(r1 - bf2f(h1)),
        f2bf(r2 - bf2f(h2)), f2bf(r3 - bf2f(h3)));
}

// ---------------------------------------------------------------------------
// Kernel 2: weight pre-convert: 6 weights -> hi planes; lo planes for w0,w1
// ---------------------------------------------------------------------------
__global__ __launch_bounds__(256) void wconv_kernel(
    const float* __restrict__ w0, const float* __restrict__ w1,
    const float* __restrict__ w2, const float* __restrict__ w3,
    const float* __restrict__ w4, const float* __restrict__ w5,
    ushort* __restrict__ whi, ushort* __restrict__ wlo)
{
    const int wi = blockIdx.y;
    const float* W = wi == 0 ? w0 : wi == 1 ? w1 : wi == 2 ? w2 :
                     wi == 3 ? w3 : wi == 4 ? w4 : w5;
    int i = blockIdx.x * 256 + threadIdx.x;   // 0..65535 float4
    float4 v = reinterpret_cast<const float4*>(W)[i];
    ushort h0 = f2bf(v.x), h1 = f2bf(v.y), h2 = f2bf(v.z), h3 = f2bf(v.w);
    reinterpret_cast<ushort4*>(whi + (size_t)wi * 262144)[i] =
        make_ushort4(h0, h1, h2, h3);
    if (wi < 2) {
        reinterpret_cast<ushort4*>(wlo + (size_t)wi * 262144)[i] =
            make_ushort4(f2bf(v.x - bf2f(h0)), f2bf(v.y - bf2f(h1)),
                         f2bf(v.z - bf2f(h2)), f2bf(v.w - bf2f(h3)));
    }
}

#define GBM 64
#define GBN 128

// ---------------------------------------------------------------------------
// Kernel 3a: fused split-precision Q+K GEMM. Both outputs share the same
// A (xh/xl): stage A once, stage Bq/Bk hi/lo (80 KB LDS -> 2 blocks/CU),
// half the barrier count of two separate kernels. hh->hl->lh order per
// 32-k block per output -> bit-identical to the separate-kernel version.
// aLo = element offset hi->lo plane of A; wLo = hi->lo of W; wK = Wq->Wk.
// ---------------------------------------------------------------------------
__global__ __launch_bounds__(256, 2) void gemm_qk(
    const ushort* __restrict__ Axh, long aLo,
    const ushort* __restrict__ Wh0, long wLo, long wK,
    const float* __restrict__ bq, const float* __restrict__ bk,
    ushort* __restrict__ Qh, ushort* __restrict__ Ql,
    ushort* __restrict__ Kh, ushort* __restrict__ Kl)
{
    __shared__ ushort sAh[GBM * 64];       //  8 KB
    __shared__ ushort sAl[GBM * 64];       //  8 KB
    __shared__ ushort sBh[2][GBN * 64];    // 16 KB x2  [0]=q [1]=k
    __shared__ ushort sBl[2][GBN * 64];    // 16 KB x2

    const int nx  = gridDim.x >> 3;
    const int bid = blockIdx.x;
    const int lt  = (bid & 7) * nx + (bid >> 3);
    const int rowBase = (lt >> 2) * GBM;
    const int colBase = (lt & 3) * GBN;

    const int tid  = threadIdx.x;
    const int lane = tid & 63;
    const int wid  = tid >> 6;
    const int q    = lane >> 4;
    const int fr   = lane & 15;
    const int wm   = wid & 1;
    const int wn   = wid >> 1;

    // pre-swizzled staging sources (same pattern as the SPLIT path)
    const ushort* asrc[2];
    const ushort* bsrc[4];
    #pragma unroll
    for (int c = 0; c < 2; ++c) {
        const int p   = wid * 2048 + c * 1024 + lane * 16;
        const int row = p >> 7;
        const int ss  = ((p >> 4) & 7) ^ (row & 7);
        asrc[c] = Axh + (size_t)(rowBase + row) * FF + ss * 8;
    }
    #pragma unroll
    for (int c = 0; c < 4; ++c) {
        const int p   = wid * 4096 + c * 1024 + lane * 16;
        const int row = p >> 7;
        const int ss  = ((p >> 4) & 7) ^ (row & 7);
        bsrc[c] = Wh0 + (size_t)(colBase + row) * FF + ss * 8;
    }

    f32x4 accQ[2][4], accK[2][4];
    #pragma unroll
    for (int mi = 0; mi < 2; ++mi)
        #pragma unroll
        for (int ni = 0; ni < 4; ++ni) {
            accQ[mi][ni] = (f32x4){0.f, 0.f, 0.f, 0.f};
            accK[mi][ni] = (f32x4){0.f, 0.f, 0.f, 0.f};
        }

    const int swz = fr & 7;

    for (int step = 0; step < 8; ++step) {
        #pragma unroll
        for (int c = 0; c < 2; ++c) {
            gload_lds16(asrc[c],       &sAh[wid * 1024 + c * 512]);
            gload_lds16(asrc[c] + aLo, &sAl[wid * 1024 + c * 512]);
            asrc[c] += 64;
        }
        #pragma unroll
        for (int c = 0; c < 4; ++c) {
            gload_lds16(bsrc[c],            &sBh[0][wid * 2048 + c * 512]);
            gload_lds16(bsrc[c] + wLo,      &sBl[0][wid * 2048 + c * 512]);
            gload_lds16(bsrc[c] + wK,       &sBh[1][wid * 2048 + c * 512]);
            gload_lds16(bsrc[c] + wK + wLo, &sBl[1][wid * 2048 + c * 512]);
            bsrc[c] += 64;
        }
        __syncthreads();   // drains vmcnt -> staged slab visible

        #pragma unroll
        for (int ksub = 0; ksub < 2; ++ksub) {
            const int kq = (ksub * 4 + q) ^ swz;
            short8 ah[2], al[2];
            #pragma unroll
            for (int mi = 0; mi < 2; ++mi) {
                ah[mi] = *(const short8*)&sAh[(wm * 32 + mi * 16 + fr) * 64 + (kq << 3)];
                al[mi] = *(const short8*)&sAl[(wm * 32 + mi * 16 + fr) * 64 + (kq << 3)];
            }
            __builtin_amdgcn_s_setprio(1);
            #pragma unroll
            for (int qk = 0; qk < 2; ++qk) {
                short8 bh[4], bl[4];
                #pragma unroll
                for (int ni = 0; ni < 4; ++ni) {
                    bh[ni] = *(const short8*)&sBh[qk][(wn * 64 + ni * 16 + fr) * 64 + (kq << 3)];
                    bl[ni] = *(const short8*)&sBl[qk][(wn * 64 + ni * 16 + fr) * 64 + (kq << 3)];
                }
                f32x4 (*acc)[4] = qk == 0 ? accQ : accK;
                // hh
                #pragma unroll
                for (int mi = 0; mi < 2; ++mi)
                    #pragma unroll
                    for (int ni = 0; ni < 4; ++ni)
                        acc[mi][ni] = __builtin_amdgcn_mfma_f32_16x16x32_bf16(
                            ah[mi], bh[ni], acc[mi][ni], 0, 0, 0);
                // hl
                #pragma unroll
                for (int mi = 0; mi < 2; ++mi)
                    #pragma unroll
                    for (int ni = 0; ni < 4; ++ni)
                        acc[mi][ni] = __builtin_amdgcn_mfma_f32_16x16x32_bf16(
                            ah[mi], bl[ni], acc[mi][ni], 0, 0, 0);
                // lh
                #pragma unroll
                for (int mi = 0; mi < 2; ++mi)
                    #pragma unroll
                    for (int ni = 0; ni < 4; ++ni)
                        acc[mi][ni] = __builtin_amdgcn_mfma_f32_16x16x32_bf16(
                            al[mi], bh[ni], acc[mi][ni], 0, 0, 0);
            }
            __builtin_amdgcn_s_setprio(0);
        }
        __syncthreads();   // reads done before next slab overwrites
    }

    // epilogue: C/D layout col=lane&15, row=(lane>>4)*4+reg
    #pragma unroll
    for (int mi = 0; mi < 2; ++mi)
        #pragma unroll
        for (int ni = 0; ni < 4; ++ni) {
            const int col = colBase + wn * 64 + ni * 16 + fr;
            const float bqc = bq[col];
            const float bkc = bk[col];
            #pragma unroll
            for (int r = 0; r < 4; ++r) {
                const int row = rowBase + wm * 32 + mi * 16 + q * 4 + r;
                const size_t idx = (size_t)row * FF + col;
                float vq = accQ[mi][ni][r] + bqc;
                ushort hq = f2bf(vq);
                Qh[idx] = hq;
                Ql[idx] = f2bf(vq - bf2f(hq));
                float vk = accK[mi][ni][r] + bkc;
                ushort hk = f2bf(vk);
                Kh[idx] = hk;
                Kl[idx] = f2bf(vk - bf2f(hk));
            }
        }
}

// ---------------------------------------------------------------------------
// Kernel 3b: MFMA GEMM (non-split). C = A[M,512] * W[512,512]^T + bias
// Tile 64x128, BK=128, 4 steps (sA 16KB, sB 32KB).
// EPI: 0 none, 1 relu, 2 +addsrc. OUT: 0 fp32; 1 bf16.
// ---------------------------------------------------------------------------
template <int EPI, int OUT>
__global__ __launch_bounds__(256, 2) void gemm_mfma2(
    const ushort* __restrict__ Ah, const ushort* __restrict__ Wh,
    const float* __restrict__ bias, const float* __restrict__ addsrc,
    float* __restrict__ Cf, ushort* __restrict__ Cb)
{
    __shared__ ushort sA[GBM * 128];   // 16 KB
    __shared__ ushort sB[GBN * 128];   // 32 KB

    const int nx  = gridDim.x >> 3;
    const int bid = blockIdx.x;
    const int lt  = (bid & 7) * nx + (bid >> 3);
    const int rowBase = (lt >> 2) * GBM;
    const int colBase = (lt & 3) * GBN;

    const int tid  = threadIdx.x;
    const int lane = tid & 63;
    const int wid  = tid >> 6;
    const int q    = lane >> 4;
    const int fr   = lane & 15;
    const int wm   = wid & 1;
    const int wn   = wid >> 1;

    const ushort* asrc[4];
    const ushort* bsrc[8];
    #pragma unroll
    for (int c = 0; c < 4; ++c) {
        const int p   = wid * 4096 + c * 1024 + lane * 16;
        const int row = p >> 8;
        const int ss  = ((p >> 4) & 15) ^ (row & 7);
        asrc[c] = Ah + (size_t)(rowBase + row) * FF + ss * 8;
    }
    #pragma unroll
    for (int c = 0; c < 8; ++c) {
        const int p   = wid * 8192 + c * 1024 + lane * 16;
        const int row = p >> 8;
        const int ss  = ((p >> 4) & 15) ^ (row & 7);
        bsrc[c] = Wh + (size_t)(colBase + row) * FF + ss * 8;
    }

    f32x4 acc[2][4];
    #pragma unroll
    for (int mi = 0; mi < 2; ++mi)
        #pragma unroll
        for (int ni = 0; ni < 4; ++ni) acc[mi][ni] = (f32x4){0.f, 0.f, 0.f, 0.f};

    const int swz = fr & 7;

    for (int step = 0; step < 4; ++step) {
        #pragma unroll
        for (int c = 0; c < 4; ++c) {
            gload_lds16(asrc[c], &sA[wid * 2048 + c * 512]);
            asrc[c] += 128;
        }
        #pragma unroll
        for (int c = 0; c < 8; ++c) {
            gload_lds16(bsrc[c], &sB[wid * 4096 + c * 512]);
            bsrc[c] += 128;
        }
        __syncthreads();

        #pragma unroll
        for (int ksub = 0; ksub < 4; ++ksub) {
            const int kq = (ksub * 4 + q) ^ swz;   // low-3-bit XOR only
            short8 af[2], bf[4];
            #pragma unroll
            for (int mi = 0; mi < 2; ++mi)
                af[mi] = *(const short8*)&sA[(wm * 32 + mi * 16 + fr) * 128 + (kq << 3)];
            #pragma unroll
            for (int ni = 0; ni < 4; ++ni)
                bf[ni] = *(const short8*)&sB[(wn * 64 + ni * 16 + fr) * 128 + (kq << 3)];
            #pragma unroll
            for (int mi = 0; mi < 2; ++mi)
                #pragma unroll
                for (int ni = 0; ni < 4; ++ni)
                    acc[mi][ni] = __builtin_amdgcn_mfma_f32_16x16x32_bf16(
                        af[mi], bf[ni], acc[mi][ni], 0, 0, 0);
        }
        __syncthreads();
    }

    #pragma unroll
    for (int mi = 0; mi < 2; ++mi)
        #pragma unroll
        for (int ni = 0; ni < 4; ++ni) {
            const int col = colBase + wn * 64 + ni * 16 + fr;
            const float bcol = bias[col];
            #pragma unroll
            for (int r = 0; r < 4; ++r) {
                const int row = rowBase + wm * 32 + mi * 16 + q * 4 + r;
                float v = acc[mi][ni][r] + bcol;
                if (EPI == 1) v = fmaxf(v, 0.0f);
                if (EPI == 2) v += addsrc[(size_t)row * FF + col];
                const size_t idx = (size_t)row * FF + col;
                if (OUT == 0) Cf[idx] = v;
                if (OUT == 1) Cb[idx] = f2bf(v);
            }
        }
}

// ---------------------------------------------------------------------------
// Kernel 4: qks + M. 16 lanes per (hbt,n), 4 d's per lane.
// ---------------------------------------------------------------------------
__global__ __launch_bounds__(256) void qks_M_kernel(
    const ushort* __restrict__ Qh, const ushort* __restrict__ Ql,
    const ushort* __restrict__ Kh, const ushort* __restrict__ Kl,
    const int* __restrict__ adj, const float* __restrict__ w_proj,
    const float* __restrict__ b_proj, float* __restrict__ Mout)
{
    const int unit = blockIdx.x * 16 + (threadIdx.x >> 4);  // (hbt, n)
    const int l16  = threadIdx.x & 15;
    const int n    = unit & (NN - 1);
    const int hbt  = unit >> 9;
    const int h    = hbt / BTOT;
    const int bt   = hbt - h * BTOT;

    const uint headbase = (uint)(bt * NN) * FF + h * DH + l16 * 4;
    const ushort* khB = Kh + headbase;
    const ushort* klB = Kl + headbase;

    const int   aj = adj[n * KADJ + l16];
    f32x4 acc = (f32x4){0.f, 0.f, 0.f, 0.f};

    #pragma unroll
    for (int k = 0; k < KADJ; ++k) {
        const int  j   = __shfl(aj, k, 16);
        const float wk = w_proj[k];
        const uint off = (uint)j * FF;
        uint2 hu = *(const uint2*)(khB + off);
        uint2 lu = *(const uint2*)(klB + off);
        float k0 = __uint_as_float(hu.x << 16) + __uint_as_float(lu.x << 16);
        float k1 = __uint_as_float(hu.x & 0xFFFF0000u) +
                   __uint_as_float(lu.x & 0xFFFF0000u);
        float k2 = __uint_as_float(hu.y << 16) + __uint_as_float(lu.y << 16);
        float k3 = __uint_as_float(hu.y & 0xFFFF0000u) +
                   __uint_as_float(lu.y & 0xFFFF0000u);
        acc[0] += wk * k0; acc[1] += wk * k1;
        acc[2] += wk * k2; acc[3] += wk * k3;
    }

    const uint qidx = headbase + (uint)n * FF;
    uint2 qhu = *(const uint2*)(Qh + qidx);
    uint2 qlu = *(const uint2*)(Ql + qidx);
    float q0 = __uint_as_float(qhu.x << 16) + __uint_as_float(qlu.x << 16);
    float q1 = __uint_as_float(qhu.x & 0xFFFF0000u) +
               __uint_as_float(qlu.x & 0xFFFF0000u);
    float q2 = __uint_as_float(qhu.y << 16) + __uint_as_float(qlu.y << 16);
    float q3 = __uint_as_float(qhu.y & 0xFFFF0000u) +
               __uint_as_float(qlu.y & 0xFFFF0000u);
    float t = q0 * acc[0] + q1 * acc[1] + q2 * acc[2] + q3 * acc[3];
    #pragma unroll
    for (int o = 1; o <= 8; o <<= 1) t += __shfl_xor(t, o);
    if (l16 == 0) Mout[unit] = t + b_proj[0];
}

// ---------------------------------------------------------------------------
// Kernel 5: top-27 by rank counting. One block per g, one thread per n.
// ---------------------------------------------------------------------------
__global__ __launch_bounds__(512) void topk_kernel(
    const float* __restrict__ M, int* __restrict__ mtop)
{
    __shared__ float vals[NN];
    const int g = blockIdx.x;
    const int n = threadIdx.x;
    const float m = M[(size_t)g * NN + n];
    vals[n] = m;
    __syncthreads();

    int cnt = 0;
    #pragma unroll 16
    for (int j = 0; j < NN; ++j) {
        const float vj = vals[j];
        cnt += (vj > m || (vj == m && j < n)) ? 1 : 0;
    }
    if (cnt < SN_) mtop[g * SN_ + cnt] = n;
}

// ---------------------------------------------------------------------------
// Kernel 6: fused attention per g = (h,bt). 1024 threads = 16 waves.
// ---------------------------------------------------------------------------
__global__ __launch_bounds__(1024) void fused_attn(
    const ushort* __restrict__ Qh, const ushort* __restrict__ Ql,
    const ushort* __restrict__ Kh, const ushort* __restrict__ Kl,
    const ushort* __restrict__ Vb, const int* __restrict__ mtop,
    ushort* __restrict__ attnout)
{
    __shared__ ushort P_lds[32 * 512];    // 32 KB, XOR-swizzled by row
    __shared__ ushort Vt_lds[64 * 512];   // 64 KB, Vt[d][n], XOR-swizzled by d
    __shared__ float red0[16][32];
    __shared__ float red1[16][32];
    __shared__ float val2[2][32][68];     // PV k-half partials
    __shared__ int   cp_lds[NN];
    __shared__ int   mt[32];

    const int g = blockIdx.x;
    const int h = g / BTOT, bt = g % BTOT;
    const int tid = threadIdx.x;
    const int wave = tid >> 6, lane = tid & 63;
    const int q = lane >> 4, c = lane & 15;
    const size_t base_bt = (size_t)bt * NN * FF;
    const int hcol = h * DH;

    if (tid < 32) mt[tid] = mtop[g * SN_ + (tid < SN_ ? tid : 0)];
    __syncthreads();   // only the mt load is outstanding here

    // ---- K fragments: wave owns 32-col slice, direct ushort8 loads ----
    const int n0 = wave * 32;
    short8 bfh[2][2], bfl[2][2];
    #pragma unroll
    for (int nt = 0; nt < 2; ++nt) {
        const size_t kp = base_bt + (size_t)(n0 + nt * 16 + c) * FF + hcol + q * 8;
        #pragma unroll
        for (int ks = 0; ks < 2; ++ks) {
            bfh[nt][ks] = *(const short8*)&Kh[kp + ks * 32];
            bfl[nt][ks] = *(const short8*)&Kl[kp + ks * 32];
        }
    }

    // ---- V loads (bf16): 2 units/thread, consumed after softmax ----
    ushort4 vreg[2][4];
    #pragma unroll
    for (int i = 0; i < 2; ++i) {
        const int u  = tid + i * 1024;
        const int d4 = u & 15, ng = u >> 4;   // ng in [0,128)
        #pragma unroll
        for (int ii = 0; ii < 4; ++ii)
            vreg[i][ii] = *(const ushort4*)&Vb[base_bt +
                (size_t)(ng * 4 + ii) * FF + hcol + d4 * 4];
    }

    // ---- Q fragments (gather via mt) ----
    short8 afh[2][2], afl[2][2];
    #pragma unroll
    for (int m = 0; m < 2; ++m) {
        const int grow = mt[m * 16 + c];
        const size_t qp = base_bt + (size_t)grow * FF + hcol + q * 8;
        #pragma unroll
        for (int ks = 0; ks < 2; ++ks) {
            afh[m][ks] = *(const short8*)&Qh[qp + ks * 32];
            afl[m][ks] = *(const short8*)&Ql[qp + ks * 32];
        }
    }

    // ---- scores (split: hh + hl + lh), scale 1/8 ----
    f32x4 sc[2][2];
    #pragma unroll
    for (int m = 0; m < 2; ++m)
        #pragma unroll
        for (int nt = 0; nt < 2; ++nt) sc[m][nt] = (f32x4){0.f, 0.f, 0.f, 0.f};
    __builtin_amdgcn_s_setprio(1);
    #pragma unroll
    for (int ks = 0; ks < 2; ++ks)
        #pragma unroll
        for (int m = 0; m < 2; ++m)
            #pragma unroll
            for (int nt = 0; nt < 2; ++nt) {
                sc[m][nt] = __builtin_amdgcn_mfma_f32_16x16x32_bf16(
                    afh[m][ks], bfh[nt][ks], sc[m][nt], 0, 0, 0);
                sc[m][nt] = __builtin_amdgcn_mfma_f32_16x16x32_bf16(
                    afh[m][ks], bfl[nt][ks], sc[m][nt], 0, 0, 0);
                sc[m][nt] = __builtin_amdgcn_mfma_f32_16x16x32_bf16(
                    afl[m][ks], bfh[nt][ks], sc[m][nt], 0, 0, 0);
            }
    __builtin_amdgcn_s_setprio(0);
    #pragma unroll
    for (int m = 0; m < 2; ++m)
        #pragma unroll
        for (int nt = 0; nt < 2; ++nt)
            #pragma unroll
            for (int r = 0; r < 4; ++r) sc[m][nt][r] *= 0.125f;

    // ---- row max (rows = m*16 + q*4 + r), shfl over c then LDS over waves ----
    float rmax[2][4];
    #pragma unroll
    for (int m = 0; m < 2; ++m)
        #pragma unroll
        for (int r = 0; r < 4; ++r)
            rmax[m][r] = fmaxf(sc[m][0][r], sc[m][1][r]);
    #pragma unroll
    for (int off = 1; off <= 8; off <<= 1)
        #pragma unroll
        for (int m = 0; m < 2; ++m)
            #pragma unroll
            for (int r = 0; r < 4; ++r)
                rmax[m][r] = fmaxf(rmax[m][r], __shfl_xor(rmax[m][r], off));
    if (c == 0) {
        #pragma unroll
        for (int m = 0; m < 2; ++m)
            #pragma unroll
            for (int r = 0; r < 4; ++r)
                red0[wave][m * 16 + q * 4 + r] = rmax[m][r];
    }
    __syncthreads();
    float gmax[2][4];
    #pragma unroll
    for (int m = 0; m < 2; ++m)
        #pragma unroll
        for (int r = 0; r < 4; ++r) {
            const int row = m * 16 + q * 4 + r;
            float v = red0[0][row];
            #pragma unroll
            for (int w = 1; w < 16; ++w) v = fmaxf(v, red0[w][row]);
            gmax[m][r] = v;
        }

    // ---- exp + row sum ----
    float rsum[2][4] = {};
    #pragma unroll
    for (int m = 0; m < 2; ++m)
        #pragma unroll
        for (int nt = 0; nt < 2; ++nt)
            #pragma unroll
            for (int r = 0; r < 4; ++r) {
                float e = expf(sc[m][nt][r] - gmax[m][r]);
                sc[m][nt][r] = e;
                rsum[m][r] += e;
            }
    #pragma unroll
    for (int off = 1; off <= 8; off <<= 1)
        #pragma unroll
        for (int m = 0; m < 2; ++m)
            #pragma unroll
            for (int r = 0; r < 4; ++r)
                rsum[m][r] += __shfl_xor(rsum[m][r], off);
    if (c == 0) {
        #pragma unroll
        for (int m = 0; m < 2; ++m)
            #pragma unroll
            for (int r = 0; r < 4; ++r)
                red1[wave][m * 16 + q * 4 + r] = rsum[m][r];
    }
    __syncthreads();
    #pragma unroll
    for (int m = 0; m < 2; ++m)
        #pragma unroll
        for (int r = 0; r < 4; ++r) {
            const int row = m * 16 + q * 4 + r;
            float s = red1[0][row];
            #pragma unroll
            for (int w = 1; w < 16; ++w) s += red1[w][row];
            const float inv = 1.0f / s;
            #pragma unroll
            for (int nt = 0; nt < 2; ++nt) sc[m][nt][r] *= inv;
        }

    // ---- cp argmax over rows < 27, per column ----
    #pragma unroll
    for (int nt = 0; nt < 2; ++nt) {
        float bv = -INFINITY;
        int bi = 1 << 30;
        #pragma unroll
        for (int m = 0; m < 2; ++m)
            #pragma unroll
            for (int r = 0; r < 4; ++r) {
                const int row = m * 16 + q * 4 + r;
                if (row < SN_) {
                    float v = sc[m][nt][r];
                    if (v > bv) { bv = v; bi = row; }
                }
            }
        #pragma unroll
        for (int off = 16; off <= 32; off <<= 1) {
            float ov = __shfl_xor(bv, off);
            int   oi = __shfl_xor(bi, off);
            if (ov > bv || (ov == bv && oi < bi)) { bv = ov; bi = oi; }
        }
        if (q == 0) cp_lds[n0 + nt * 16 + c] = bi;
    }

    // ---- write P (bf16) to swizzled LDS ----
    #pragma unroll
    for (int m = 0; m < 2; ++m)
        #pragma unroll
        for (int nt = 0; nt < 2; ++nt)
            #pragma unroll
            for (int r = 0; r < 4; ++r) {
                const int row = m * 16 + q * 4 + r;
                const int col = n0 + nt * 16 + c;
                P_lds[(row * 512 + col) ^ ((row & 7) << 3)] = f2bf(sc[m][nt][r]);
            }

    // ---- transpose-write V into Vt_lds ----
    #pragma unroll
    for (int i = 0; i < 2; ++i) {
        const int u  = tid + i * 1024;
        const int d4 = u & 15, ng = u >> 4;
        const int n0v = ng * 4;
        #pragma unroll
        for (int j = 0; j < 4; ++j) {
            const int d = d4 * 4 + j;
            ushort4 t;
            t.x = ((const ushort*)&vreg[i][0])[j];
            t.y = ((const ushort*)&vreg[i][1])[j];
            t.z = ((const ushort*)&vreg[i][2])[j];
            t.w = ((const ushort*)&vreg[i][3])[j];
            *(ushort4*)&Vt_lds[(d * 512 + n0v) ^ ((d & 7) << 3)] = t;
        }
    }
    __syncthreads();

    // ---- PV: wave = (kh, msel, dt); k-half 256 each ----
    const int kh = wave >> 3, rem = wave & 7;
    const int msel = rem >> 2, dt = rem & 3;
    const int dcol = dt * 16 + c;
    const int prow = msel * 16 + c;
    const int pswz = (prow & 7) << 3;
    const int vswz = (dcol & 7) << 3;
    f32x4 acc = (f32x4){0.f, 0.f, 0.f, 0.f};
    __builtin_amdgcn_s_setprio(1);
    #pragma unroll
    for (int ks8 = 0; ks8 < 8; ++ks8) {
        const int kstep = kh * 8 + ks8;
        short8 a = *(const short8*)&P_lds[(prow * 512 + kstep * 32 + q * 8) ^ pswz];
        short8 b = *(const short8*)&Vt_lds[(dcol * 512 + kstep * 32 + q * 8) ^ vswz];
        acc = __builtin_amdgcn_mfma_f32_16x16x32_bf16(a, b, acc, 0, 0, 0);
    }
    __builtin_amdgcn_s_setprio(0);
    #pragma unroll
    for (int r = 0; r < 4; ++r)
        val2[kh][msel * 16 + q * 4 + r][dt * 16 + c] = acc[r];
    __syncthreads();

    // ---- scatter: attnout[n][hcol+d] = val[cp[n]][d] (bf16) ----
    #pragma unroll
    for (int pass = 0; pass < 4; ++pass) {
        const int n  = pass * 128 + (tid >> 3);
        const int s  = cp_lds[n];
        const int d0 = (tid & 7) * 8;
        float vr[8];
        #pragma unroll
        for (int j = 0; j < 8; ++j)
            vr[j] = val2[0][s][d0 + j] + val2[1][s][d0 + j];
        uint4 u;
        u.x = (uint)f2bf(vr[0]) | ((uint)f2bf(vr[1]) << 16);
        u.y = (uint)f2bf(vr[2]) | ((uint)f2bf(vr[3]) << 16);
        u.z = (uint)f2bf(vr[4]) | ((uint)f2bf(vr[5]) << 16);
        u.w = (uint)f2bf(vr[6]) | ((uint)f2bf(vr[7]) << 16);
        *(uint4*)(attnout + base_bt + (size_t)n * FF + hcol + d0) = u;
    }
}

// ---------------------------------------------------------------------------
// Kernel 7: LayerNorm over last dim. BFOUT adds a bf16 copy of the result.
// ---------------------------------------------------------------------------
template <int AFFINE, int BFOUT>
__global__ __launch_bounds__(256) void ln_kernel(
    const float* __restrict__ X, const float* __restrict__ g,
    const float* __restrict__ b, float* __restrict__ Yf,
    ushort* __restrict__ Yb, int rows)
{
    const int row = blockIdx.x * 4 + (threadIdx.x >> 6);
    if (row >= rows) return;
    const int lane = threadIdx.x & 63;
    const float4* x4 = reinterpret_cast<const float4*>(X + (size_t)row * FF);
    float4 a = x4[lane];
    float4 c = x4[lane + 64];
    float s = a.x + a.y + a.z + a.w + c.x + c.y + c.z + c.w;
    float q = a.x * a.x + a.y * a.y + a.z * a.z + a.w * a.w +
              c.x * c.x + c.y * c.y + c.z * c.z + c.w * c.w;
    #pragma unroll
    for (int o = 32; o; o >>= 1) {
        s += __shfl_xor(s, o);
        q += __shfl_xor(q, o);
    }
    const float mu   = s * (1.0f / FF);
    const float var  = q * (1.0f / FF) - mu * mu;
    const float rstd = 1.0f / sqrtf(var + EPS_);

    float4 ya, yc;
    ya.x = (a.x - mu) * rstd; ya.y = (a.y - mu) * rstd;
    ya.z = (a.z - mu) * rstd; ya.w = (a.w - mu) * rstd;
    yc.x = (c.x - mu) * rstd; yc.y = (c.y - mu) * rstd;
    yc.z = (c.z - mu) * rstd; yc.w = (c.w - mu) * rstd;
    if (AFFINE) {
        float4 ga = reinterpret_cast<const float4*>(g)[lane];
        float4 gc = reinterpret_cast<const float4*>(g)[lane + 64];
        float4 ba = reinterpret_cast<const float4*>(b)[lane];
        float4 bc = reinterpret_cast<const float4*>(b)[lane + 64];
        ya.x = ya.x * ga.x + ba.x; ya.y = ya.y * ga.y + ba.y;
        ya.z = ya.z * ga.z + ba.z; ya.w = ya.w * ga.w + ba.w;
        yc.x = yc.x * gc.x + bc.x; yc.y = yc.y * gc.y + bc.y;
        yc.z = yc.z * gc.z + bc.z; yc.w = yc.w * gc.w + bc.w;
    }
    float4* y4 = reinterpret_cast<float4*>(Yf + (size_t)row * FF);
    y4[lane]      = ya;
    y4[lane + 64] = yc;
    if (BFOUT) {
        ushort4* yb = reinterpret_cast<ushort4*>(Yb + (size_t)row * FF);
        yb[lane] = make_ushort4(f2bf(ya.x), f2bf(ya.y), f2bf(ya.z), f2bf(ya.w));
        yb[lane + 64] = make_ushort4(f2bf(yc.x), f2bf(yc.y), f2bf(yc.z), f2bf(yc.w));
    }
}

// ---------------------------------------------------------------------------
// Launch
// ---------------------------------------------------------------------------
extern "C" void kernel_launch(void* const* d_in, const int* in_sizes, int n_in,
                              void* d_out, int out_size, void* d_ws, size_t ws_size,
                              hipStream_t stream)
{
    const float* x       = (const float*)d_in[0];
    const float* spa_val = (const float*)d_in[1];
    const float* spa_vec = (const float*)d_in[2];
    const float* tem_val = (const float*)d_in[3];
    const float* tem_vec = (const float*)d_in[4];
    const int*   adj     = (const int*)  d_in[5];
    const float* Wq = (const float*)d_in[6];  const float* bq = (const float*)d_in[7];
    const float* Wk = (const float*)d_in[8];  const float* bk = (const float*)d_in[9];
    const float* Wv = (const float*)d_in[10]; const float* bv = (const float*)d_in[11];
    const float* Wo = (const float*)d_in[12]; const float* bo = (const float*)d_in[13];
    const float* w_proj = (const float*)d_in[14];
    const float* b_proj = (const float*)d_in[15];
    const float* gamma  = (const float*)d_in[16];
    const float* beta   = (const float*)d_in[17];
    const float* W1 = (const float*)d_in[18]; const float* b1 = (const float*)d_in[19];
    const float* W2 = (const float*)d_in[20]; const float* b2 = (const float*)d_in[21];

    float* out = (float*)d_out;

    const size_t R = (size_t)ROWS * FF;   // 6,291,456

    // ws layout (ushorts)
    ushort* ws_u = (ushort*)d_ws;
    ushort* bufQh = ws_u;                 // [0, R)
    ushort* bufQl = ws_u + R;             // [R, 2R)
    ushort* bufKh = ws_u + 2 * R;         // [2R, 3R)
    ushort* bufKl = ws_u + 3 * R;         // [3R, 4R)
    ushort* bufVb = ws_u + 4 * R;         // [4R, 5R)
    ushort* whi   = ws_u + 5 * R;         // 6 * 262144
    ushort* wlo   = whi + 6 * 262144;     // 2 * 262144
    float*  Mbuf  = (float*)(wlo + 2 * 262144);          // 98,304 floats
    int*    mtop  = (int*)(Mbuf + (size_t)H_ * BTOT * NN);

    // fp32 reuse of dead plane regions
    float* o_f32 = (float*)bufQh;   // after Q planes dead
    float* v_f32 = (float*)bufKh;   // after K planes dead
    float* h2_f32 = (float*)bufQh;  // after o consumed

    // d_out scratch timeline
    ushort* xh  = (ushort*)d_out;
    ushort* xl  = xh + R;
    ushort* attnout = xh;   // after x_ dead
    ushort* vbf = xl;
    ushort* h1b = xh;       // after attnout dead

    // 1. x_ -> bf16 hi/lo planes
    add_pos_bf16<<<(ROWS * FF / 4) / 256, 256, 0, stream>>>(
        x, spa_val, spa_vec, tem_val, tem_vec, xh, xl);

    // 2. weight pre-convert
    wconv_kernel<<<dim3(256, 6), 256, 0, stream>>>(Wq, Wk, Wv, Wo, W1, W2, whi, wlo);

    // 3. Q+K fused split GEMM, then V (plain bf16)
    const int NG = (ROWS / GBM) * (FF / GBN);   // 768
    gemm_qk<<<NG, 256, 0, stream>>>(xh, (long)R,
                                    whi, (long)(6 * 262144), (long)262144,
                                    bq, bk, bufQh, bufQl, bufKh, bufKl);
    gemm_mfma2<0, 1><<<NG, 256, 0, stream>>>(xh, whi + 2 * 262144, bv, nullptr,
                                             nullptr, bufVb);

    // 4. M scores + top-27 (rank-count selection)
    qks_M_kernel<<<(H_ * BTOT * NN) / 16, 256, 0, stream>>>(
        bufQh, bufQl, bufKh, bufKl, adj, w_proj, b_proj, Mbuf);
    topk_kernel<<<H_ * BTOT, 512, 0, stream>>>(Mbuf, mtop);

    // 5. fused attention -> attnout (bf16)
    fused_attn<<<H_ * BTOT, 1024, 0, stream>>>(
        bufQh, bufQl, bufKh, bufKl, bufVb, mtop, attnout);

    // 6. output projection + LN + FFN
    gemm_mfma2<0, 0><<<NG, 256, 0, stream>>>(attnout, whi + 3 * 262144, bo, nullptr,
                                             o_f32, nullptr);
    ln_kernel<1, 1><<<ROWS / 4, 256, 0, stream>>>(o_f32, gamma, beta, v_f32, vbf, ROWS);
    gemm_mfma2<1, 1><<<NG, 256, 0, stream>>>(vbf, whi + 4 * 262144, b1, nullptr,
                                             nullptr, h1b);
    gemm_mfma2<2, 0><<<NG, 256, 0, stream>>>(h1b, whi + 5 * 262144, b2, v_f32,
                                             h2_f32, nullptr);
    ln_kernel<0, 0><<<ROWS / 4, 256, 0, stream>>>(h2_f32, nullptr, nullptr, out, nullptr, ROWS);
}

// Round 12
// 206.468 us; speedup vs baseline: 1.0255x; 1.0255x over previous
//
#include <hip/hip_runtime.h>
#include <math.h>

// Problem constants
#define H_    8
#define DH    64
#define NN    512
#define KADJ  16
#define FF    512      // H_*Dh
#define BTOT  24       // B*T
#define ROWS  12288    // B*T*N
#define SN_   27
#define EPS_  1e-5f

typedef short short8 __attribute__((ext_vector_type(8)));
typedef float f32x4  __attribute__((ext_vector_type(4)));

__device__ __forceinline__ ushort f2bf(float x) {
    uint u = __float_as_uint(x);
    u += 0x7FFFu + ((u >> 16) & 1u);
    return (ushort)(u >> 16);
}
__device__ __forceinline__ float bf2f(ushort h) {
    return __uint_as_float(((uint)h) << 16);
}

// async global->LDS, 16B per lane; LDS dest = wave-uniform base + lane*16
__device__ __forceinline__ void gload_lds16(const ushort* g, ushort* l) {
    __builtin_amdgcn_global_load_lds(
        (const __attribute__((address_space(1))) unsigned int*)g,
        (__attribute__((address_space(3))) unsigned int*)l,
        16, 0, 0);
}

// ---------------------------------------------------------------------------
// Kernel 1: x_ = x + pos, emitted directly as bf16 hi/lo planes
// ---------------------------------------------------------------------------
__global__ __launch_bounds__(256) void add_pos_bf16(
    const float* __restrict__ x,
    const float* __restrict__ spa_val, const float* __restrict__ spa_vec,
    const float* __restrict__ tem_val, const float* __restrict__ tem_vec,
    ushort* __restrict__ xh, ushort* __restrict__ xl)
{
    int i = blockIdx.x * 256 + threadIdx.x;   // float4 index, 1,572,864 total
    int f4  = i & 127;
    int row = i >> 7;
    int n   = row & (NN - 1);

    float4 xv = reinterpret_cast<const float4*>(x)[i];
    float4 sv = reinterpret_cast<const float4*>(spa_vec)[n * 128 + f4];
    float4 tv = reinterpret_cast<const float4*>(tem_vec)[n * 128 + f4];
    float4 se = reinterpret_cast<const float4*>(spa_val)[f4];
    float4 te = reinterpret_cast<const float4*>(tem_val)[f4];
    float r0 = xv.x + sv.x * se.x + tv.x * te.x;
    float r1 = xv.y + sv.y * se.y + tv.y * te.y;
    float r2 = xv.z + sv.z * se.z + tv.z * te.z;
    float r3 = xv.w + sv.w * se.w + tv.w * te.w;
    ushort h0 = f2bf(r0), h1 = f2bf(r1), h2 = f2bf(r2), h3 = f2bf(r3);
    reinterpret_cast<ushort4*>(xh)[i] = make_ushort4(h0, h1, h2, h3);
    reinterpret_cast<ushort4*>(xl)[i] = make_ushort4(
        f2bf(r0 - bf2f(h0)), f2bf(r1 - bf2f(h1)),
        f2bf(r2 - bf2f(h2)), f2bf(r3 - bf2f(h3)));
}

// ---------------------------------------------------------------------------
// Kernel 2: weight pre-convert: 6 weights -> hi planes; lo planes for w0,w1
// ---------------------------------------------------------------------------
__global__ __launch_bounds__(256) void wconv_kernel(
    const float* __restrict__ w0, const float* __restrict__ w1,
    const float* __restrict__ w2, const float* __restrict__ w3,
    const float* __restrict__ w4, const float* __restrict__ w5,
    ushort* __restrict__ whi, ushort* __restrict__ wlo)
{
    const int wi = blockIdx.y;
    const float* W = wi == 0 ? w0 : wi == 1 ? w1 : wi == 2 ? w2 :
                     wi == 3 ? w3 : wi == 4 ? w4 : w5;
    int i = blockIdx.x * 256 + threadIdx.x;   // 0..65535 float4
    float4 v = reinterpret_cast<const float4*>(W)[i];
    ushort h0 = f2bf(v.x), h1 = f2bf(v.y), h2 = f2bf(v.z), h3 = f2bf(v.w);
    reinterpret_cast<ushort4*>(whi + (size_t)wi * 262144)[i] =
        make_ushort4(h0, h1, h2, h3);
    if (wi < 2) {
        reinterpret_cast<ushort4*>(wlo + (size_t)wi * 262144)[i] =
            make_ushort4(f2bf(v.x - bf2f(h0)), f2bf(v.y - bf2f(h1)),
                         f2bf(v.z - bf2f(h2)), f2bf(v.w - bf2f(h3)));
    }
}

#define GBM 64
#define GBN 128

// ---------------------------------------------------------------------------
// Kernel 3a: fused split-precision Q+K GEMM (same A). 80 KB LDS, 2 blocks/CU.
// hh->hl->lh order per 32-k block per output -> bit-identical numerics.
// ---------------------------------------------------------------------------
__global__ __launch_bounds__(256, 2) void gemm_qk(
    const ushort* __restrict__ Axh, long aLo,
    const ushort* __restrict__ Wh0, long wLo, long wK,
    const float* __restrict__ bq, const float* __restrict__ bk,
    ushort* __restrict__ Qh, ushort* __restrict__ Ql,
    ushort* __restrict__ Kh, ushort* __restrict__ Kl)
{
    __shared__ ushort sAh[GBM * 64];       //  8 KB
    __shared__ ushort sAl[GBM * 64];       //  8 KB
    __shared__ ushort sBh[2][GBN * 64];    // 16 KB x2  [0]=q [1]=k
    __shared__ ushort sBl[2][GBN * 64];    // 16 KB x2

    const int nx  = gridDim.x >> 3;
    const int bid = blockIdx.x;
    const int lt  = (bid & 7) * nx + (bid >> 3);
    const int rowBase = (lt >> 2) * GBM;
    const int colBase = (lt & 3) * GBN;

    const int tid  = threadIdx.x;
    const int lane = tid & 63;
    const int wid  = tid >> 6;
    const int q    = lane >> 4;
    const int fr   = lane & 15;
    const int wm   = wid & 1;
    const int wn   = wid >> 1;

    const ushort* asrc[2];
    const ushort* bsrc[4];
    #pragma unroll
    for (int c = 0; c < 2; ++c) {
        const int p   = wid * 2048 + c * 1024 + lane * 16;
        const int row = p >> 7;
        const int ss  = ((p >> 4) & 7) ^ (row & 7);
        asrc[c] = Axh + (size_t)(rowBase + row) * FF + ss * 8;
    }
    #pragma unroll
    for (int c = 0; c < 4; ++c) {
        const int p   = wid * 4096 + c * 1024 + lane * 16;
        const int row = p >> 7;
        const int ss  = ((p >> 4) & 7) ^ (row & 7);
        bsrc[c] = Wh0 + (size_t)(colBase + row) * FF + ss * 8;
    }

    f32x4 accQ[2][4], accK[2][4];
    #pragma unroll
    for (int mi = 0; mi < 2; ++mi)
        #pragma unroll
        for (int ni = 0; ni < 4; ++ni) {
            accQ[mi][ni] = (f32x4){0.f, 0.f, 0.f, 0.f};
            accK[mi][ni] = (f32x4){0.f, 0.f, 0.f, 0.f};
        }

    const int swz = fr & 7;

    for (int step = 0; step < 8; ++step) {
        #pragma unroll
        for (int c = 0; c < 2; ++c) {
            gload_lds16(asrc[c],       &sAh[wid * 1024 + c * 512]);
            gload_lds16(asrc[c] + aLo, &sAl[wid * 1024 + c * 512]);
            asrc[c] += 64;
        }
        #pragma unroll
        for (int c = 0; c < 4; ++c) {
            gload_lds16(bsrc[c],            &sBh[0][wid * 2048 + c * 512]);
            gload_lds16(bsrc[c] + wLo,      &sBl[0][wid * 2048 + c * 512]);
            gload_lds16(bsrc[c] + wK,       &sBh[1][wid * 2048 + c * 512]);
            gload_lds16(bsrc[c] + wK + wLo, &sBl[1][wid * 2048 + c * 512]);
            bsrc[c] += 64;
        }
        __syncthreads();   // drains vmcnt -> staged slab visible

        #pragma unroll
        for (int ksub = 0; ksub < 2; ++ksub) {
            const int kq = (ksub * 4 + q) ^ swz;
            short8 ah[2], al[2];
            #pragma unroll
            for (int mi = 0; mi < 2; ++mi) {
                ah[mi] = *(const short8*)&sAh[(wm * 32 + mi * 16 + fr) * 64 + (kq << 3)];
                al[mi] = *(const short8*)&sAl[(wm * 32 + mi * 16 + fr) * 64 + (kq << 3)];
            }
            #pragma unroll
            for (int qk = 0; qk < 2; ++qk) {
                short8 bh[4], bl[4];
                #pragma unroll
                for (int ni = 0; ni < 4; ++ni) {
                    bh[ni] = *(const short8*)&sBh[qk][(wn * 64 + ni * 16 + fr) * 64 + (kq << 3)];
                    bl[ni] = *(const short8*)&sBl[qk][(wn * 64 + ni * 16 + fr) * 64 + (kq << 3)];
                }
                f32x4 (*acc)[4] = qk == 0 ? accQ : accK;
                // hh
                #pragma unroll
                for (int mi = 0; mi < 2; ++mi)
                    #pragma unroll
                    for (int ni = 0; ni < 4; ++ni)
                        acc[mi][ni] = __builtin_amdgcn_mfma_f32_16x16x32_bf16(
                            ah[mi], bh[ni], acc[mi][ni], 0, 0, 0);
                // hl
                #pragma unroll
                for (int mi = 0; mi < 2; ++mi)
                    #pragma unroll
                    for (int ni = 0; ni < 4; ++ni)
                        acc[mi][ni] = __builtin_amdgcn_mfma_f32_16x16x32_bf16(
                            ah[mi], bl[ni], acc[mi][ni], 0, 0, 0);
                // lh
                #pragma unroll
                for (int mi = 0; mi < 2; ++mi)
                    #pragma unroll
                    for (int ni = 0; ni < 4; ++ni)
                        acc[mi][ni] = __builtin_amdgcn_mfma_f32_16x16x32_bf16(
                            al[mi], bh[ni], acc[mi][ni], 0, 0, 0);
            }
        }
        __syncthreads();   // reads done before next slab overwrites
    }

    // epilogue: C/D layout col=lane&15, row=(lane>>4)*4+reg
    #pragma unroll
    for (int mi = 0; mi < 2; ++mi)
        #pragma unroll
        for (int ni = 0; ni < 4; ++ni) {
            const int col = colBase + wn * 64 + ni * 16 + fr;
            const float bqc = bq[col];
            const float bkc = bk[col];
            #pragma unroll
            for (int r = 0; r < 4; ++r) {
                const int row = rowBase + wm * 32 + mi * 16 + q * 4 + r;
                const size_t idx = (size_t)row * FF + col;
                float vq = accQ[mi][ni][r] + bqc;
                ushort hq = f2bf(vq);
                Qh[idx] = hq;
                Ql[idx] = f2bf(vq - bf2f(hq));
                float vk = accK[mi][ni][r] + bkc;
                ushort hk = f2bf(vk);
                Kh[idx] = hk;
                Kl[idx] = f2bf(vk - bf2f(hk));
            }
        }
}

// ---------------------------------------------------------------------------
// Kernel 3b: MFMA GEMM (non-split). C = A[M,512] * W[512,512]^T + bias
// Tile 64x128, BK=128, 4 steps (sA 16KB, sB 32KB).
// EPI: 0 none, 1 relu, 2 +bf16 addsrc. OUT: 0 fp32; 1 bf16.
// ---------------------------------------------------------------------------
template <int EPI, int OUT>
__global__ __launch_bounds__(256, 2) void gemm_mfma2(
    const ushort* __restrict__ Ah, const ushort* __restrict__ Wh,
    const float* __restrict__ bias, const ushort* __restrict__ addsrc_bf,
    float* __restrict__ Cf, ushort* __restrict__ Cb)
{
    __shared__ ushort sA[GBM * 128];   // 16 KB
    __shared__ ushort sB[GBN * 128];   // 32 KB

    const int nx  = gridDim.x >> 3;
    const int bid = blockIdx.x;
    const int lt  = (bid & 7) * nx + (bid >> 3);
    const int rowBase = (lt >> 2) * GBM;
    const int colBase = (lt & 3) * GBN;

    const int tid  = threadIdx.x;
    const int lane = tid & 63;
    const int wid  = tid >> 6;
    const int q    = lane >> 4;
    const int fr   = lane & 15;
    const int wm   = wid & 1;
    const int wn   = wid >> 1;

    const ushort* asrc[4];
    const ushort* bsrc[8];
    #pragma unroll
    for (int c = 0; c < 4; ++c) {
        const int p   = wid * 4096 + c * 1024 + lane * 16;
        const int row = p >> 8;
        const int ss  = ((p >> 4) & 15) ^ (row & 7);
        asrc[c] = Ah + (size_t)(rowBase + row) * FF + ss * 8;
    }
    #pragma unroll
    for (int c = 0; c < 8; ++c) {
        const int p   = wid * 8192 + c * 1024 + lane * 16;
        const int row = p >> 8;
        const int ss  = ((p >> 4) & 15) ^ (row & 7);
        bsrc[c] = Wh + (size_t)(colBase + row) * FF + ss * 8;
    }

    f32x4 acc[2][4];
    #pragma unroll
    for (int mi = 0; mi < 2; ++mi)
        #pragma unroll
        for (int ni = 0; ni < 4; ++ni) acc[mi][ni] = (f32x4){0.f, 0.f, 0.f, 0.f};

    const int swz = fr & 7;

    for (int step = 0; step < 4; ++step) {
        #pragma unroll
        for (int c = 0; c < 4; ++c) {
            gload_lds16(asrc[c], &sA[wid * 2048 + c * 512]);
            asrc[c] += 128;
        }
        #pragma unroll
        for (int c = 0; c < 8; ++c) {
            gload_lds16(bsrc[c], &sB[wid * 4096 + c * 512]);
            bsrc[c] += 128;
        }
        __syncthreads();

        #pragma unroll
        for (int ksub = 0; ksub < 4; ++ksub) {
            const int kq = (ksub * 4 + q) ^ swz;   // low-3-bit XOR only
            short8 af[2], bf[4];
            #pragma unroll
            for (int mi = 0; mi < 2; ++mi)
                af[mi] = *(const short8*)&sA[(wm * 32 + mi * 16 + fr) * 128 + (kq << 3)];
            #pragma unroll
            for (int ni = 0; ni < 4; ++ni)
                bf[ni] = *(const short8*)&sB[(wn * 64 + ni * 16 + fr) * 128 + (kq << 3)];
            #pragma unroll
            for (int mi = 0; mi < 2; ++mi)
                #pragma unroll
                for (int ni = 0; ni < 4; ++ni)
                    acc[mi][ni] = __builtin_amdgcn_mfma_f32_16x16x32_bf16(
                        af[mi], bf[ni], acc[mi][ni], 0, 0, 0);
        }
        __syncthreads();
    }

    #pragma unroll
    for (int mi = 0; mi < 2; ++mi)
        #pragma unroll
        for (int ni = 0; ni < 4; ++ni) {
            const int col = colBase + wn * 64 + ni * 16 + fr;
            const float bcol = bias[col];
            #pragma unroll
            for (int r = 0; r < 4; ++r) {
                const int row = rowBase + wm * 32 + mi * 16 + q * 4 + r;
                float v = acc[mi][ni][r] + bcol;
                if (EPI == 1) v = fmaxf(v, 0.0f);
                const size_t idx = (size_t)row * FF + col;
                if (EPI == 2) v += bf2f(addsrc_bf[idx]);
                if (OUT == 0) Cf[idx] = v;
                if (OUT == 1) Cb[idx] = f2bf(v);
            }
        }
}

// ---------------------------------------------------------------------------
// Kernel 4: qks + M. 16 lanes per (hbt,n), 4 d's per lane.
// ---------------------------------------------------------------------------
__global__ __launch_bounds__(256) void qks_M_kernel(
    const ushort* __restrict__ Qh, const ushort* __restrict__ Ql,
    const ushort* __restrict__ Kh, const ushort* __restrict__ Kl,
    const int* __restrict__ adj, const float* __restrict__ w_proj,
    const float* __restrict__ b_proj, float* __restrict__ Mout)
{
    const int unit = blockIdx.x * 16 + (threadIdx.x >> 4);  // (hbt, n)
    const int l16  = threadIdx.x & 15;
    const int n    = unit & (NN - 1);
    const int hbt  = unit >> 9;
    const int h    = hbt / BTOT;
    const int bt   = hbt - h * BTOT;

    const uint headbase = (uint)(bt * NN) * FF + h * DH + l16 * 4;
    const ushort* khB = Kh + headbase;
    const ushort* klB = Kl + headbase;

    const int   aj = adj[n * KADJ + l16];
    f32x4 acc = (f32x4){0.f, 0.f, 0.f, 0.f};

    #pragma unroll
    for (int k = 0; k < KADJ; ++k) {
        const int  j   = __shfl(aj, k, 16);
        const float wk = w_proj[k];
        const uint off = (uint)j * FF;
        uint2 hu = *(const uint2*)(khB + off);
        uint2 lu = *(const uint2*)(klB + off);
        float k0 = __uint_as_float(hu.x << 16) + __uint_as_float(lu.x << 16);
        float k1 = __uint_as_float(hu.x & 0xFFFF0000u) +
                   __uint_as_float(lu.x & 0xFFFF0000u);
        float k2 = __uint_as_float(hu.y << 16) + __uint_as_float(lu.y << 16);
        float k3 = __uint_as_float(hu.y & 0xFFFF0000u) +
                   __uint_as_float(lu.y & 0xFFFF0000u);
        acc[0] += wk * k0; acc[1] += wk * k1;
        acc[2] += wk * k2; acc[3] += wk * k3;
    }

    const uint qidx = headbase + (uint)n * FF;
    uint2 qhu = *(const uint2*)(Qh + qidx);
    uint2 qlu = *(const uint2*)(Ql + qidx);
    float q0 = __uint_as_float(qhu.x << 16) + __uint_as_float(qlu.x << 16);
    float q1 = __uint_as_float(qhu.x & 0xFFFF0000u) +
               __uint_as_float(qlu.x & 0xFFFF0000u);
    float q2 = __uint_as_float(qhu.y << 16) + __uint_as_float(qlu.y << 16);
    float q3 = __uint_as_float(qhu.y & 0xFFFF0000u) +
               __uint_as_float(qlu.y & 0xFFFF0000u);
    float t = q0 * acc[0] + q1 * acc[1] + q2 * acc[2] + q3 * acc[3];
    #pragma unroll
    for (int o = 1; o <= 8; o <<= 1) t += __shfl_xor(t, o);
    if (l16 == 0) Mout[unit] = t + b_proj[0];
}

// ---------------------------------------------------------------------------
// Kernel 5: top-27 by rank counting. One block per g, one thread per n.
// ---------------------------------------------------------------------------
__global__ __launch_bounds__(512) void topk_kernel(
    const float* __restrict__ M, int* __restrict__ mtop)
{
    __shared__ float vals[NN];
    const int g = blockIdx.x;
    const int n = threadIdx.x;
    const float m = M[(size_t)g * NN + n];
    vals[n] = m;
    __syncthreads();

    int cnt = 0;
    #pragma unroll 16
    for (int j = 0; j < NN; ++j) {
        const float vj = vals[j];
        cnt += (vj > m || (vj == m && j < n)) ? 1 : 0;
    }
    if (cnt < SN_) mtop[g * SN_ + cnt] = n;
}

// ---------------------------------------------------------------------------
// Kernel 6: fused attention per g = (h,bt). 1024 threads = 16 waves.
// ---------------------------------------------------------------------------
__global__ __launch_bounds__(1024) void fused_attn(
    const ushort* __restrict__ Qh, const ushort* __restrict__ Ql,
    const ushort* __restrict__ Kh, const ushort* __restrict__ Kl,
    const ushort* __restrict__ Vb, const int* __restrict__ mtop,
    ushort* __restrict__ attnout)
{
    __shared__ ushort P_lds[32 * 512];    // 32 KB, XOR-swizzled by row
    __shared__ ushort Vt_lds[64 * 512];   // 64 KB, Vt[d][n], XOR-swizzled by d
    __shared__ float red0[16][32];
    __shared__ float red1[16][32];
    __shared__ float val2[2][32][68];     // PV k-half partials
    __shared__ int   cp_lds[NN];
    __shared__ int   mt[32];

    const int g = blockIdx.x;
    const int h = g / BTOT, bt = g % BTOT;
    const int tid = threadIdx.x;
    const int wave = tid >> 6, lane = tid & 63;
    const int q = lane >> 4, c = lane & 15;
    const size_t base_bt = (size_t)bt * NN * FF;
    const int hcol = h * DH;

    if (tid < 32) mt[tid] = mtop[g * SN_ + (tid < SN_ ? tid : 0)];
    __syncthreads();   // only the mt load is outstanding here

    // ---- K fragments: wave owns 32-col slice, direct ushort8 loads ----
    const int n0 = wave * 32;
    short8 bfh[2][2], bfl[2][2];
    #pragma unroll
    for (int nt = 0; nt < 2; ++nt) {
        const size_t kp = base_bt + (size_t)(n0 + nt * 16 + c) * FF + hcol + q * 8;
        #pragma unroll
        for (int ks = 0; ks < 2; ++ks) {
            bfh[nt][ks] = *(const short8*)&Kh[kp + ks * 32];
            bfl[nt][ks] = *(const short8*)&Kl[kp + ks * 32];
        }
    }

    // ---- V loads (bf16): 2 units/thread, consumed after softmax ----
    ushort4 vreg[2][4];
    #pragma unroll
    for (int i = 0; i < 2; ++i) {
        const int u  = tid + i * 1024;
        const int d4 = u & 15, ng = u >> 4;   // ng in [0,128)
        #pragma unroll
        for (int ii = 0; ii < 4; ++ii)
            vreg[i][ii] = *(const ushort4*)&Vb[base_bt +
                (size_t)(ng * 4 + ii) * FF + hcol + d4 * 4];
    }

    // ---- Q fragments (gather via mt) ----
    short8 afh[2][2], afl[2][2];
    #pragma unroll
    for (int m = 0; m < 2; ++m) {
        const int grow = mt[m * 16 + c];
        const size_t qp = base_bt + (size_t)grow * FF + hcol + q * 8;
        #pragma unroll
        for (int ks = 0; ks < 2; ++ks) {
            afh[m][ks] = *(const short8*)&Qh[qp + ks * 32];
            afl[m][ks] = *(const short8*)&Ql[qp + ks * 32];
        }
    }

    // ---- scores (split: hh + hl + lh), scale 1/8 ----
    f32x4 sc[2][2];
    #pragma unroll
    for (int m = 0; m < 2; ++m)
        #pragma unroll
        for (int nt = 0; nt < 2; ++nt) sc[m][nt] = (f32x4){0.f, 0.f, 0.f, 0.f};
    __builtin_amdgcn_s_setprio(1);
    #pragma unroll
    for (int ks = 0; ks < 2; ++ks)
        #pragma unroll
        for (int m = 0; m < 2; ++m)
            #pragma unroll
            for (int nt = 0; nt < 2; ++nt) {
                sc[m][nt] = __builtin_amdgcn_mfma_f32_16x16x32_bf16(
                    afh[m][ks], bfh[nt][ks], sc[m][nt], 0, 0, 0);
                sc[m][nt] = __builtin_amdgcn_mfma_f32_16x16x32_bf16(
                    afh[m][ks], bfl[nt][ks], sc[m][nt], 0, 0, 0);
                sc[m][nt] = __builtin_amdgcn_mfma_f32_16x16x32_bf16(
                    afl[m][ks], bfh[nt][ks], sc[m][nt], 0, 0, 0);
            }
    __builtin_amdgcn_s_setprio(0);
    #pragma unroll
    for (int m = 0; m < 2; ++m)
        #pragma unroll
        for (int nt = 0; nt < 2; ++nt)
            #pragma unroll
            for (int r = 0; r < 4; ++r) sc[m][nt][r] *= 0.125f;

    // ---- row max (rows = m*16 + q*4 + r), shfl over c then LDS over waves ----
    float rmax[2][4];
    #pragma unroll
    for (int m = 0; m < 2; ++m)
        #pragma unroll
        for (int r = 0; r < 4; ++r)
            rmax[m][r] = fmaxf(sc[m][0][r], sc[m][1][r]);
    #pragma unroll
    for (int off = 1; off <= 8; off <<= 1)
        #pragma unroll
        for (int m = 0; m < 2; ++m)
            #pragma unroll
            for (int r = 0; r < 4; ++r)
                rmax[m][r] = fmaxf(rmax[m][r], __shfl_xor(rmax[m][r], off));
    if (c == 0) {
        #pragma unroll
        for (int m = 0; m < 2; ++m)
            #pragma unroll
            for (int r = 0; r < 4; ++r)
                red0[wave][m * 16 + q * 4 + r] = rmax[m][r];
    }
    __syncthreads();
    float gmax[2][4];
    #pragma unroll
    for (int m = 0; m < 2; ++m)
        #pragma unroll
        for (int r = 0; r < 4; ++r) {
            const int row = m * 16 + q * 4 + r;
            float v = red0[0][row];
            #pragma unroll
            for (int w = 1; w < 16; ++w) v = fmaxf(v, red0[w][row]);
            gmax[m][r] = v;
        }

    // ---- exp + row sum ----
    float rsum[2][4] = {};
    #pragma unroll
    for (int m = 0; m < 2; ++m)
        #pragma unroll
        for (int nt = 0; nt < 2; ++nt)
            #pragma unroll
            for (int r = 0; r < 4; ++r) {
                float e = expf(sc[m][nt][r] - gmax[m][r]);
                sc[m][nt][r] = e;
                rsum[m][r] += e;
            }
    #pragma unroll
    for (int off = 1; off <= 8; off <<= 1)
        #pragma unroll
        for (int m = 0; m < 2; ++m)
            #pragma unroll
            for (int r = 0; r < 4; ++r)
                rsum[m][r] += __shfl_xor(rsum[m][r], off);
    if (c == 0) {
        #pragma unroll
        for (int m = 0; m < 2; ++m)
            #pragma unroll
            for (int r = 0; r < 4; ++r)
                red1[wave][m * 16 + q * 4 + r] = rsum[m][r];
    }
    __syncthreads();
    #pragma unroll
    for (int m = 0; m < 2; ++m)
        #pragma unroll
        for (int r = 0; r < 4; ++r) {
            const int row = m * 16 + q * 4 + r;
            float s = red1[0][row];
            #pragma unroll
            for (int w = 1; w < 16; ++w) s += red1[w][row];
            const float inv = 1.0f / s;
            #pragma unroll
            for (int nt = 0; nt < 2; ++nt) sc[m][nt][r] *= inv;
        }

    // ---- cp argmax over rows < 27, per column ----
    #pragma unroll
    for (int nt = 0; nt < 2; ++nt) {
        float bv = -INFINITY;
        int bi = 1 << 30;
        #pragma unroll
        for (int m = 0; m < 2; ++m)
            #pragma unroll
            for (int r = 0; r < 4; ++r) {
                const int row = m * 16 + q * 4 + r;
                if (row < SN_) {
                    float v = sc[m][nt][r];
                    if (v > bv) { bv = v; bi = row; }
                }
            }
        #pragma unroll
        for (int off = 16; off <= 32; off <<= 1) {
            float ov = __shfl_xor(bv, off);
            int   oi = __shfl_xor(bi, off);
            if (ov > bv || (ov == bv && oi < bi)) { bv = ov; bi = oi; }
        }
        if (q == 0) cp_lds[n0 + nt * 16 + c] = bi;
    }

    // ---- write P (bf16) to swizzled LDS ----
    #pragma unroll
    for (int m = 0; m < 2; ++m)
        #pragma unroll
        for (int nt = 0; nt < 2; ++nt)
            #pragma unroll
            for (int r = 0; r < 4; ++r) {
                const int row = m * 16 + q * 4 + r;
                const int col = n0 + nt * 16 + c;
                P_lds[(row * 512 + col) ^ ((row & 7) << 3)] = f2bf(sc[m][nt][r]);
            }

    // ---- transpose-write V into Vt_lds ----
    #pragma unroll
    for (int i = 0; i < 2; ++i) {
        const int u  = tid + i * 1024;
        const int d4 = u & 15, ng = u >> 4;
        const int n0v = ng * 4;
        #pragma unroll
        for (int j = 0; j < 4; ++j) {
            const int d = d4 * 4 + j;
            ushort4 t;
            t.x = ((const ushort*)&vreg[i][0])[j];
            t.y = ((const ushort*)&vreg[i][1])[j];
            t.z = ((const ushort*)&vreg[i][2])[j];
            t.w = ((const ushort*)&vreg[i][3])[j];
            *(ushort4*)&Vt_lds[(d * 512 + n0v) ^ ((d & 7) << 3)] = t;
        }
    }
    __syncthreads();

    // ---- PV: wave = (kh, msel, dt); k-half 256 each ----
    const int kh = wave >> 3, rem = wave & 7;
    const int msel = rem >> 2, dt = rem & 3;
    const int dcol = dt * 16 + c;
    const int prow = msel * 16 + c;
    const int pswz = (prow & 7) << 3;
    const int vswz = (dcol & 7) << 3;
    f32x4 acc = (f32x4){0.f, 0.f, 0.f, 0.f};
    __builtin_amdgcn_s_setprio(1);
    #pragma unroll
    for (int ks8 = 0; ks8 < 8; ++ks8) {
        const int kstep = kh * 8 + ks8;
        short8 a = *(const short8*)&P_lds[(prow * 512 + kstep * 32 + q * 8) ^ pswz];
        short8 b = *(const short8*)&Vt_lds[(dcol * 512 + kstep * 32 + q * 8) ^ vswz];
        acc = __builtin_amdgcn_mfma_f32_16x16x32_bf16(a, b, acc, 0, 0, 0);
    }
    __builtin_amdgcn_s_setprio(0);
    #pragma unroll
    for (int r = 0; r < 4; ++r)
        val2[kh][msel * 16 + q * 4 + r][dt * 16 + c] = acc[r];
    __syncthreads();

    // ---- scatter: attnout[n][hcol+d] = val[cp[n]][d] (bf16) ----
    #pragma unroll
    for (int pass = 0; pass < 4; ++pass) {
        const int n  = pass * 128 + (tid >> 3);
        const int s  = cp_lds[n];
        const int d0 = (tid & 7) * 8;
        float vr[8];
        #pragma unroll
        for (int j = 0; j < 8; ++j)
            vr[j] = val2[0][s][d0 + j] + val2[1][s][d0 + j];
        uint4 u;
        u.x = (uint)f2bf(vr[0]) | ((uint)f2bf(vr[1]) << 16);
        u.y = (uint)f2bf(vr[2]) | ((uint)f2bf(vr[3]) << 16);
        u.z = (uint)f2bf(vr[4]) | ((uint)f2bf(vr[5]) << 16);
        u.w = (uint)f2bf(vr[6]) | ((uint)f2bf(vr[7]) << 16);
        *(uint4*)(attnout + base_bt + (size_t)n * FF + hcol + d0) = u;
    }
}

// ---------------------------------------------------------------------------
// Kernel 7: LayerNorm over last dim, bf16 input. OUTF32=1 -> fp32 out,
// else bf16 out. Stats computed in fp32. One wave per row, 4 rows/block.
// ---------------------------------------------------------------------------
template <int AFFINE, int OUTF32>
__global__ __launch_bounds__(256) void ln_bf_kernel(
    const ushort* __restrict__ X, const float* __restrict__ g,
    const float* __restrict__ b, float* __restrict__ Yf,
    ushort* __restrict__ Yb, int rows)
{
    const int row = blockIdx.x * 4 + (threadIdx.x >> 6);
    if (row >= rows) return;
    const int lane = threadIdx.x & 63;

    ushort4 u0 = *(const ushort4*)&X[(size_t)row * FF + lane * 8];
    ushort4 u1 = *(const ushort4*)&X[(size_t)row * FF + lane * 8 + 4];
    float f[8];
    f[0] = bf2f(u0.x); f[1] = bf2f(u0.y); f[2] = bf2f(u0.z); f[3] = bf2f(u0.w);
    f[4] = bf2f(u1.x); f[5] = bf2f(u1.y); f[6] = bf2f(u1.z); f[7] = bf2f(u1.w);

    float s = 0.f, qq = 0.f;
    #pragma unroll
    for (int j = 0; j < 8; ++j) { s += f[j]; qq += f[j] * f[j]; }
    #pragma unroll
    for (int o = 32; o; o >>= 1) {
        s  += __shfl_xor(s, o);
        qq += __shfl_xor(qq, o);
    }
    const float mu   = s * (1.0f / FF);
    const float var  = qq * (1.0f / FF) - mu * mu;
    const float rstd = 1.0f / sqrtf(var + EPS_);

    float y[8];
    #pragma unroll
    for (int j = 0; j < 8; ++j) y[j] = (f[j] - mu) * rstd;
    if (AFFINE) {
        float4 ga = *(const float4*)&g[lane * 8];
        float4 gb = *(const float4*)&g[lane * 8 + 4];
        float4 ba = *(const float4*)&b[lane * 8];
        float4 bb = *(const float4*)&b[lane * 8 + 4];
        y[0] = y[0] * ga.x + ba.x; y[1] = y[1] * ga.y + ba.y;
        y[2] = y[2] * ga.z + ba.z; y[3] = y[3] * ga.w + ba.w;
        y[4] = y[4] * gb.x + bb.x; y[5] = y[5] * gb.y + bb.y;
        y[6] = y[6] * gb.z + bb.z; y[7] = y[7] * gb.w + bb.w;
    }
    if (OUTF32) {
        float4* yo = (float4*)&Yf[(size_t)row * FF + lane * 8];
        yo[0] = make_float4(y[0], y[1], y[2], y[3]);
        yo[1] = make_float4(y[4], y[5], y[6], y[7]);
    } else {
        uint4 u;
        u.x = (uint)f2bf(y[0]) | ((uint)f2bf(y[1]) << 16);
        u.y = (uint)f2bf(y[2]) | ((uint)f2bf(y[3]) << 16);
        u.z = (uint)f2bf(y[4]) | ((uint)f2bf(y[5]) << 16);
        u.w = (uint)f2bf(y[6]) | ((uint)f2bf(y[7]) << 16);
        *(uint4*)&Yb[(size_t)row * FF + lane * 8] = u;
    }
}

// ---------------------------------------------------------------------------
// Launch
// ---------------------------------------------------------------------------
extern "C" void kernel_launch(void* const* d_in, const int* in_sizes, int n_in,
                              void* d_out, int out_size, void* d_ws, size_t ws_size,
                              hipStream_t stream)
{
    const float* x       = (const float*)d_in[0];
    const float* spa_val = (const float*)d_in[1];
    const float* spa_vec = (const float*)d_in[2];
    const float* tem_val = (const float*)d_in[3];
    const float* tem_vec = (const float*)d_in[4];
    const int*   adj     = (const int*)  d_in[5];
    const float* Wq = (const float*)d_in[6];  const float* bq = (const float*)d_in[7];
    const float* Wk = (const float*)d_in[8];  const float* bk = (const float*)d_in[9];
    const float* Wv = (const float*)d_in[10]; const float* bv = (const float*)d_in[11];
    const float* Wo = (const float*)d_in[12]; const float* bo = (const float*)d_in[13];
    const float* w_proj = (const float*)d_in[14];
    const float* b_proj = (const float*)d_in[15];
    const float* gamma  = (const float*)d_in[16];
    const float* beta   = (const float*)d_in[17];
    const float* W1 = (const float*)d_in[18]; const float* b1 = (const float*)d_in[19];
    const float* W2 = (const float*)d_in[20]; const float* b2 = (const float*)d_in[21];

    float* out = (float*)d_out;

    const size_t R = (size_t)ROWS * FF;   // 6,291,456

    // ws layout (ushorts)
    ushort* ws_u = (ushort*)d_ws;
    ushort* bufQh = ws_u;                 // [0, R)
    ushort* bufQl = ws_u + R;             // [R, 2R)
    ushort* bufKh = ws_u + 2 * R;         // [2R, 3R)
    ushort* bufKl = ws_u + 3 * R;         // [3R, 4R)
    ushort* bufVb = ws_u + 4 * R;         // [4R, 5R)
    ushort* whi   = ws_u + 5 * R;         // 6 * 262144
    ushort* wlo   = whi + 6 * 262144;     // 2 * 262144
    float*  Mbuf  = (float*)(wlo + 2 * 262144);          // 98,304 floats
    int*    mtop  = (int*)(Mbuf + (size_t)H_ * BTOT * NN);

    // bf16 reuse of dead plane regions
    ushort* o_bf  = bufQh;   // after Q planes dead (Wo output)
    ushort* h2_bf = bufKh;   // after K planes dead (W2 output)

    // d_out scratch timeline
    ushort* xh  = (ushort*)d_out;
    ushort* xl  = xh + R;
    ushort* attnout = xh;   // after x_ dead
    ushort* vbf = xl;       // LN1 output (bf16)
    ushort* h1b = xh;       // after attnout dead (W1 output)

    // 1. x_ -> bf16 hi/lo planes
    add_pos_bf16<<<(ROWS * FF / 4) / 256, 256, 0, stream>>>(
        x, spa_val, spa_vec, tem_val, tem_vec, xh, xl);

    // 2. weight pre-convert
    wconv_kernel<<<dim3(256, 6), 256, 0, stream>>>(Wq, Wk, Wv, Wo, W1, W2, whi, wlo);

    // 3. Q+K fused split GEMM, then V (plain bf16)
    const int NG = (ROWS / GBM) * (FF / GBN);   // 768
    gemm_qk<<<NG, 256, 0, stream>>>(xh, (long)R,
                                    whi, (long)(6 * 262144), (long)262144,
                                    bq, bk, bufQh, bufQl, bufKh, bufKl);
    gemm_mfma2<0, 1><<<NG, 256, 0, stream>>>(xh, whi + 2 * 262144, bv, nullptr,
                                             nullptr, bufVb);

    // 4. M scores + top-27 (rank-count selection)
    qks_M_kernel<<<(H_ * BTOT * NN) / 16, 256, 0, stream>>>(
        bufQh, bufQl, bufKh, bufKl, adj, w_proj, b_proj, Mbuf);
    topk_kernel<<<H_ * BTOT, 512, 0, stream>>>(Mbuf, mtop);

    // 5. fused attention -> attnout (bf16)
    fused_attn<<<H_ * BTOT, 1024, 0, stream>>>(
        bufQh, bufQl, bufKh, bufKl, bufVb, mtop, attnout);

    // 6. output projection + LN + FFN (all intermediates bf16)
    gemm_mfma2<0, 1><<<NG, 256, 0, stream>>>(attnout, whi + 3 * 262144, bo, nullptr,
                                             nullptr, o_bf);
    ln_bf_kernel<1, 0><<<ROWS / 4, 256, 0, stream>>>(o_bf, gamma, beta,
                                                     nullptr, vbf, ROWS);
    gemm_mfma2<1, 1><<<NG, 256, 0, stream>>>(vbf, whi + 4 * 262144, b1, nullptr,
                                             nullptr, h1b);
    gemm_mfma2<2, 1><<<NG, 256, 0, stream>>>(h1b, whi + 5 * 262144, b2, vbf,
                                             nullptr, h2_bf);
    ln_bf_kernel<0, 1><<<ROWS / 4, 256, 0, stream>>>(h2_bf, nullptr, nullptr,
                                                     out, nullptr, ROWS);
}